// Round 6
// baseline (200.357 us; speedup 1.0000x reference)
//
#include <hip/hip_runtime.h>
#include <hip/hip_bf16.h>
#include <cstdint>

#define BB 64
#define NN 512
#define MM 1024
#define DD 128

typedef __bf16 bf16x8 __attribute__((ext_vector_type(8)));
typedef float f32x4 __attribute__((ext_vector_type(4)));

static __device__ __forceinline__ unsigned short f2bf(float f) {
    union { float f; unsigned int i; } v; v.f = f;
    unsigned int x = v.i;
    x += 0x7FFFu + ((x >> 16) & 1u);   // RNE
    return (unsigned short)(x >> 16);
}
// packed: low short = a, high short = b (v_cvt_pk_bf16_f32 on gfx950)
static __device__ __forceinline__ unsigned int f2bf2(float a, float b) {
    union { __hip_bfloat162 h; unsigned int u; } c;
    c.h = __float22bfloat162_rn(make_float2(a, b));
    return c.u;
}

// ---------- Kernel 0: W fp32->bf16 (once) + zero ctx -------------------------
__global__ __launch_bounds__(256) void wconv_kernel(
    const float* __restrict__ Uw, const float* __restrict__ Vw,
    unsigned short* __restrict__ WuB, unsigned short* __restrict__ WvB,
    float* __restrict__ ctx)   // 8192 floats
{
    int tid = blockIdx.x * 256 + threadIdx.x;          // 8192
    const float* src = (tid < 4096) ? Uw : Vw;
    unsigned short* dst = (tid < 4096) ? WuB : WvB;
    int idx = tid & 4095;
    float4 v = ((const float4*)src)[idx];
    uint2 u = { f2bf2(v.x, v.y), f2bf2(v.z, v.w) };
    ((uint2*)dst)[idx] = u;
    if (tid < 4096) ((float2*)ctx)[tid] = {0.f, 0.f};
}

// ---------- Kernel 1: Vp = relu(h_p @ Wv^T + b) ------------------------------
// Writes Vp row-major (== tiles [b][mt][64][128]) and VpT tiled [b][mt][128][64],
// both via LDS so all global stores are coalesced uint4.
__global__ __launch_bounds__(256) void proj_v_kernel(
    const float* __restrict__ X,
    const unsigned short* __restrict__ Wbf,
    const float* __restrict__ bias,
    unsigned short* __restrict__ Y,
    unsigned short* __restrict__ YT)
{
    __shared__ __align__(16) unsigned short Ws[128 * 136];   // 34816 B, reused
    unsigned short* Ys = Ws;            // 64*128 = 8192 shorts (unpadded)
    unsigned short* Ts = Ws + 8192;     // 128*72 = 9216 shorts -> 17408 total
    const int t = threadIdx.x;
    const int lane = t & 63;
    const int wave = t >> 6;
    const int n16 = lane & 15, q = lane >> 4;
    const long row0 = (long)blockIdx.x * 64;

    // stage bf16 W (32KB) coalesced
    {
        const uint4* Wg = (const uint4*)Wbf;
        #pragma unroll
        for (int i = 0; i < 8; ++i) {
            int idx = i * 256 + t;
            uint4 v = Wg[idx];
            int off = idx * 8;
            *(uint4*)&Ws[(off >> 7) * 136 + (off & 127)] = v;
        }
    }
    __syncthreads();

    f32x4 acc[8];
    #pragma unroll
    for (int j = 0; j < 8; ++j) acc[j] = {0.f, 0.f, 0.f, 0.f};

    const float* xrow = X + (row0 + wave * 16 + n16) * DD + q * 8;
    #pragma unroll
    for (int kk = 0; kk < 4; ++kk) {
        float4 x0 = *(const float4*)(xrow + kk * 32);
        float4 x1 = *(const float4*)(xrow + kk * 32 + 4);
        union { bf16x8 v; unsigned int u[4]; } a;
        a.u[0] = f2bf2(x0.x, x0.y); a.u[1] = f2bf2(x0.z, x0.w);
        a.u[2] = f2bf2(x1.x, x1.y); a.u[3] = f2bf2(x1.z, x1.w);
        #pragma unroll
        for (int j = 0; j < 8; ++j) {
            bf16x8 b = *(const bf16x8*)&Ws[(j * 16 + n16) * 136 + q * 8 + kk * 32];
            acc[j] = __builtin_amdgcn_mfma_f32_16x16x32_bf16(a.v, b, acc[j], 0, 0, 0);
        }
    }

    // bias + relu into registers
    unsigned short yb[8][4];
    #pragma unroll
    for (int j = 0; j < 8; ++j) {
        const float bv = bias[j * 16 + n16];
        float y[4];
        #pragma unroll
        for (int r = 0; r < 4; ++r) {
            float v = acc[j][r] + bv;
            y[r] = v > 0.f ? v : 0.f;
        }
        uint2 u = { f2bf2(y[0], y[1]), f2bf2(y[2], y[3]) };
        *(uint2*)&yb[j][0] = u;
    }
    __syncthreads();   // Ws reads done; reuse as Ys/Ts

    #pragma unroll
    for (int j = 0; j < 8; ++j) {
        const int e = j * 16 + n16;
        // Ys[n][e], n = wave*16 + q*4 + r (scalar b16 writes, once per block)
        #pragma unroll
        for (int r = 0; r < 4; ++r)
            Ys[(wave * 16 + q * 4 + r) * 128 + e] = yb[j][r];
        // Ts[e][m_local] packed 4 consecutive m
        *(uint2*)&Ts[e * 72 + wave * 16 + q * 4] = *(uint2*)&yb[j][0];
    }
    __syncthreads();

    // coalesced stores
    {
        uint4* dstY = (uint4*)(Y + row0 * DD);
        const long b = row0 >> 10;
        const long mt = (row0 & 1023) >> 6;
        uint4* dstT = (uint4*)(YT + ((b * 16 + mt) * 128) * 64);
        #pragma unroll
        for (int i = 0; i < 4; ++i) {
            int idx = i * 256 + t;             // 1024 uint4 each
            dstY[idx] = ((const uint4*)Ys)[idx];
            int e = idx >> 3, m = (idx & 7) * 8;
            dstT[idx] = *(const uint4*)&Ts[e * 72 + m];
        }
    }
}

// ---------- Kernel 2: fused proj_c + bilinear attention + mean ---------------
// Grid 512 = (b, nt). Block 256 = 4 waves x 16 n. Phase 1: Uc = relu(h_c Wu^T+b)
// in-register (C-layout) + LDS for QK B-frags. Phase 2: flash loop over m with
// per-lane softmax (scores >= 0 post-ReLU => no max), register prefetch of the
// next tile so global latency is off the critical path.
__global__ __launch_bounds__(256) void attn_kernel(
    const float* __restrict__ hc,             // (B*512,128) fp32
    const unsigned short* __restrict__ WuB,   // (128,128) bf16
    const float* __restrict__ Ub,             // (128) fp32
    const unsigned short* __restrict__ Vp,    // (B*1024,128) bf16
    const unsigned short* __restrict__ VpT,   // (B,16,128,64) bf16 tiled
    float* __restrict__ ctx)                  // (B,128) fp32, pre-zeroed
{
    __shared__ __align__(16) unsigned char smem[52224];
    unsigned short* Ws  = (unsigned short*)smem;      // 128*136 (phase 1)
    unsigned short* Ucs = Ws + 128 * 136;             // 64*136  (phase 1)
    unsigned short* Vs  = (unsigned short*)smem;      // 64*136  (phase 2)
    unsigned short* VTs = Vs + 64 * 136;              // 128*72  (phase 2)
    unsigned short* Ps  = VTs + 128 * 72;             // 4*16*72 (phase 2)

    const int t = threadIdx.x;
    const int lane = t & 63;
    const int wave = t >> 6;
    const int n16 = lane & 15, q = lane >> 4;

    const int id = blockIdx.x;
    const int xcd = id & 7;
    const int slot = id >> 3;
    const int b = xcd * 8 + (slot >> 3);
    const int nt = slot & 7;

    const unsigned short* vpb = Vp + (long)b * MM * DD;
    const unsigned short* vtb = VpT + (long)b * 16 * DD * 64;

    // ---- Phase 1: Uc for this block's 64 n-rows ----
    {
        const uint4* Wg = (const uint4*)WuB;
        #pragma unroll
        for (int i = 0; i < 8; ++i) {
            int idx = i * 256 + t;
            uint4 v = Wg[idx];
            int off = idx * 8;
            *(uint4*)&Ws[(off >> 7) * 136 + (off & 127)] = v;
        }
    }
    __syncthreads();

    f32x4 acc[8];
    #pragma unroll
    for (int j = 0; j < 8; ++j) acc[j] = {0.f, 0.f, 0.f, 0.f};
    {
        const float* xrow = hc + ((long)b * NN + nt * 64 + wave * 16 + n16) * DD + q * 8;
        #pragma unroll
        for (int kk = 0; kk < 4; ++kk) {
            float4 x0 = *(const float4*)(xrow + kk * 32);
            float4 x1 = *(const float4*)(xrow + kk * 32 + 4);
            union { bf16x8 v; unsigned int u[4]; } a;
            a.u[0] = f2bf2(x0.x, x0.y); a.u[1] = f2bf2(x0.z, x0.w);
            a.u[2] = f2bf2(x1.x, x1.y); a.u[3] = f2bf2(x1.z, x1.w);
            #pragma unroll
            for (int j = 0; j < 8; ++j) {
                bf16x8 bb = *(const bf16x8*)&Ws[(j * 16 + n16) * 136 + q * 8 + kk * 32];
                acc[j] = __builtin_amdgcn_mfma_f32_16x16x32_bf16(a.v, bb, acc[j], 0, 0, 0);
            }
        }
    }
    // bias+relu; keep fp32 row-sum for epilogue; bf16 copy into Ucs (n-major)
    float ucred[8];
    #pragma unroll
    for (int j = 0; j < 8; ++j) {
        const float bv = Ub[j * 16 + n16];
        float s = 0.f;
        #pragma unroll
        for (int r = 0; r < 4; ++r) {
            float v = acc[j][r] + bv;
            v = v > 0.f ? v : 0.f;
            s += v;
            Ucs[(wave * 16 + q * 4 + r) * 136 + j * 16 + n16] = f2bf(v);
        }
        ucred[j] = s;
    }
    __syncthreads();

    // QK B-frags from Ucs (read once, then LDS is free for phase 2)
    bf16x8 Bg[4];
    #pragma unroll
    for (int kk = 0; kk < 4; ++kk)
        Bg[kk] = *(const bf16x8*)&Ucs[(wave * 16 + n16) * 136 + q * 8 + kk * 32];

    // prefetch tile 0 into registers
    uint4 pa[4], pb[4];
    #pragma unroll
    for (int i = 0; i < 4; ++i) {
        pa[i] = ((const uint4*)(vpb))[i * 256 + t];
        pb[i] = ((const uint4*)(vtb))[i * 256 + t];
    }
    __syncthreads();   // Bg reads complete before staging overwrites

    f32x4 O[8];
    #pragma unroll
    for (int j = 0; j < 8; ++j) O[j] = {0.f, 0.f, 0.f, 0.f};
    float lpart = 0.f;
    const float LOG2E = 1.44269504088896f;

    for (int mt = 0; mt < 16; ++mt) {
        // write prefetched tile to LDS
        #pragma unroll
        for (int i = 0; i < 4; ++i) {
            int idx = i * 256 + t;
            int off = idx * 8;
            *(uint4*)&Vs[(off >> 7) * 136 + (off & 127)] = pa[i];
            *(uint4*)&VTs[(off >> 6) * 72 + (off & 63)] = pb[i];
        }
        // issue global prefetch for mt+1 (latency hidden behind compute)
        if (mt < 15) {
            const uint4* s1 = (const uint4*)(vpb + (mt + 1) * 64 * DD);
            const uint4* s2 = (const uint4*)(vtb + (mt + 1) * DD * 64);
            #pragma unroll
            for (int i = 0; i < 4; ++i) {
                pa[i] = s1[i * 256 + t];
                pb[i] = s2[i * 256 + t];
            }
        }
        __syncthreads();

        // S^T = Vp_tile * Uc^T : reg r -> m = j*16+q*4+r, n = n16
        f32x4 S[4];
        #pragma unroll
        for (int j = 0; j < 4; ++j) S[j] = {0.f, 0.f, 0.f, 0.f};
        #pragma unroll
        for (int kk = 0; kk < 4; ++kk) {
            #pragma unroll
            for (int j = 0; j < 4; ++j) {
                bf16x8 a = *(const bf16x8*)&Vs[(j * 16 + n16) * 136 + q * 8 + kk * 32];
                S[j] = __builtin_amdgcn_mfma_f32_16x16x32_bf16(a, Bg[kk], S[j], 0, 0, 0);
            }
        }

        // p = exp(s), per-lane only
        #pragma unroll
        for (int j = 0; j < 4; ++j) {
            float p0 = __builtin_exp2f(S[j][0] * LOG2E);
            float p1 = __builtin_exp2f(S[j][1] * LOG2E);
            float p2 = __builtin_exp2f(S[j][2] * LOG2E);
            float p3 = __builtin_exp2f(S[j][3] * LOG2E);
            lpart += (p0 + p1) + (p2 + p3);
            uint2 u = { f2bf2(p0, p1), f2bf2(p2, p3) };
            *(uint2*)&Ps[wave * (16 * 72) + n16 * 72 + j * 16 + q * 4] = u;
        }

        // O += P * V : A = Ps rows (n, k=m), B = VTs rows (d, k=m)
        #pragma unroll
        for (int kk = 0; kk < 2; ++kk) {
            bf16x8 a = *(const bf16x8*)&Ps[wave * (16 * 72) + n16 * 72 + kk * 32 + q * 8];
            #pragma unroll
            for (int j = 0; j < 8; ++j) {
                bf16x8 bb = *(const bf16x8*)&VTs[(j * 16 + n16) * 72 + kk * 32 + q * 8];
                O[j] = __builtin_amdgcn_mfma_f32_16x16x32_bf16(a, bb, O[j], 0, 0, 0);
            }
        }
        __syncthreads();
    }

    // l per n (lane n16 holds l for n = n16 after reduction)
    lpart += __shfl_xor(lpart, 16);
    lpart += __shfl_xor(lpart, 32);

    // epilogue: ctx[b][d] += Sigma_n (Uc[n][d] + O[n][d]/l[n])
    float inv[4];
    #pragma unroll
    for (int r = 0; r < 4; ++r)
        inv[r] = 1.0f / __shfl(lpart, q * 4 + r);
    #pragma unroll
    for (int j = 0; j < 8; ++j) {
        float s = ucred[j]
                + O[j][0] * inv[0] + O[j][1] * inv[1]
                + O[j][2] * inv[2] + O[j][3] * inv[3];
        s += __shfl_xor(s, 16);
        s += __shfl_xor(s, 32);
        if (q == 0)
            atomicAdd(&ctx[b * DD + j * 16 + n16], s);
    }
}

// ---------- Kernel 3: out = ctx * q / N --------------------------------------
__global__ __launch_bounds__(256) void finalize_kernel(
    const float* __restrict__ ctx, const float* __restrict__ qv,
    float* __restrict__ out)
{
    int i = blockIdx.x * 256 + threadIdx.x;
    out[i] = ctx[i] * qv[i & 127] * (1.0f / (float)NN);
}

extern "C" void kernel_launch(void* const* d_in, const int* in_sizes, int n_in,
                              void* d_out, int out_size, void* d_ws, size_t ws_size,
                              hipStream_t stream) {
    const float* h_c = (const float*)d_in[0];
    const float* h_p = (const float*)d_in[1];
    const float* U_w = (const float*)d_in[2];
    const float* U_b = (const float*)d_in[3];
    const float* V_w = (const float*)d_in[4];
    const float* V_b = (const float*)d_in[5];
    const float* qv  = (const float*)d_in[6];
    float* out = (float*)d_out;

    unsigned short* Vp  = (unsigned short*)d_ws;                        // 64*1024*128 bf16
    unsigned short* VpT = Vp  + (size_t)BB * MM * DD;                   // tiled (B,16,128,64)
    unsigned short* WuB = VpT + (size_t)BB * DD * MM;                   // 128*128 bf16
    unsigned short* WvB = WuB + (size_t)DD * DD;                        // 128*128 bf16
    float* ctx = (float*)(WvB + (size_t)DD * DD);                       // 64*128 fp32

    wconv_kernel<<<32, 256, 0, stream>>>(U_w, V_w, WuB, WvB, ctx);
    proj_v_kernel<<<BB * MM / 64, 256, 0, stream>>>(h_p, WvB, V_b, Vp, VpT);
    attn_kernel<<<512, 256, 0, stream>>>(h_c, WuB, U_b, Vp, VpT, ctx);
    finalize_kernel<<<BB * DD / 256, 256, 0, stream>>>(ctx, qv, out);
}

// Round 9
// 130.827 us; speedup vs baseline: 1.5315x; 1.5315x over previous
//
#include <hip/hip_runtime.h>
#include <hip/hip_bf16.h>
#include <cstdint>

#define BB 64
#define NN 512
#define MM 1024
#define DD 128

typedef __bf16 bf16x8 __attribute__((ext_vector_type(8)));
typedef float f32x4 __attribute__((ext_vector_type(4)));

static __device__ __forceinline__ unsigned short f2bf(float f) {
    union { float f; unsigned int i; } v; v.f = f;
    unsigned int x = v.i;
    x += 0x7FFFu + ((x >> 16) & 1u);   // RNE
    return (unsigned short)(x >> 16);
}
// packed v_cvt_pk_bf16_f32: low = a, high = b
static __device__ __forceinline__ unsigned int f2bf2(float a, float b) {
    union { __hip_bfloat162 h; unsigned int u; } c;
    c.h = __float22bfloat162_rn(make_float2(a, b));
    return c.u;
}
// async global->LDS DMA, 16 B per lane, dest = wave-uniform base + lane*16
static __device__ __forceinline__ void async16(const void* g, void* l) {
    __builtin_amdgcn_global_load_lds(
        (const __attribute__((address_space(1))) void*)g,
        (__attribute__((address_space(3))) void*)l, 16, 0, 0);
}

// ---------- Kernel 1: Vp = relu(h_p @ Wv^T + b) ------------------------------
// Outputs: Vp row-major tiles [b][mt][64][128], VpT tiled [b][mt][128][64].
__global__ __launch_bounds__(256, 4) void proj_v_kernel(
    const float* __restrict__ X,
    const float* __restrict__ Wv,
    const float* __restrict__ bias,
    unsigned short* __restrict__ Y,
    unsigned short* __restrict__ YT)
{
    __shared__ __align__(16) unsigned short Ws[128 * 136];   // 34816 B, reused
    unsigned short* Ys = Ws;            // 64*128 shorts
    unsigned short* Ts = Ws + 8192;     // 128*72 shorts
    const int t = threadIdx.x;
    const int lane = t & 63;
    const int wave = t >> 6;
    const int n16 = lane & 15, q = lane >> 4;
    const long row0 = (long)blockIdx.x * 64;

    // X loads FIRST (latency overlaps W staging below)
    float4 xv[8];
    {
        const float* xrow = X + (row0 + wave * 16 + n16) * DD + q * 8;
        #pragma unroll
        for (int kk = 0; kk < 4; ++kk) {
            xv[2 * kk]     = *(const float4*)(xrow + kk * 32);
            xv[2 * kk + 1] = *(const float4*)(xrow + kk * 32 + 4);
        }
    }

    // stage Wv fp32 -> bf16 into padded LDS
    {
        const float4* Wg = (const float4*)Wv;
        #pragma unroll
        for (int i = 0; i < 16; ++i) {
            int idx = i * 256 + t;            // 4096 float4
            float4 v = Wg[idx];
            int off = idx * 4;                // shorts
            uint2 u = { f2bf2(v.x, v.y), f2bf2(v.z, v.w) };
            *(uint2*)&Ws[(off >> 7) * 136 + (off & 127)] = u;
        }
    }
    __syncthreads();

    f32x4 acc[8];
    #pragma unroll
    for (int j = 0; j < 8; ++j) acc[j] = {0.f, 0.f, 0.f, 0.f};

    #pragma unroll
    for (int kk = 0; kk < 4; ++kk) {
        float4 x0 = xv[2 * kk], x1 = xv[2 * kk + 1];
        union { bf16x8 v; unsigned int u[4]; } a;
        a.u[0] = f2bf2(x0.x, x0.y); a.u[1] = f2bf2(x0.z, x0.w);
        a.u[2] = f2bf2(x1.x, x1.y); a.u[3] = f2bf2(x1.z, x1.w);
        #pragma unroll
        for (int j = 0; j < 8; ++j) {
            bf16x8 b = *(const bf16x8*)&Ws[(j * 16 + n16) * 136 + q * 8 + kk * 32];
            acc[j] = __builtin_amdgcn_mfma_f32_16x16x32_bf16(a.v, b, acc[j], 0, 0, 0);
        }
    }

    unsigned short yb[8][4];
    #pragma unroll
    for (int j = 0; j < 8; ++j) {
        const float bv = bias[j * 16 + n16];
        float y[4];
        #pragma unroll
        for (int r = 0; r < 4; ++r) {
            float v = acc[j][r] + bv;
            y[r] = v > 0.f ? v : 0.f;
        }
        uint2 u = { f2bf2(y[0], y[1]), f2bf2(y[2], y[3]) };
        *(uint2*)&yb[j][0] = u;
    }
    __syncthreads();   // Ws reads done; reuse as Ys/Ts

    #pragma unroll
    for (int j = 0; j < 8; ++j) {
        const int e = j * 16 + n16;
        #pragma unroll
        for (int r = 0; r < 4; ++r)
            Ys[(wave * 16 + q * 4 + r) * 128 + e] = yb[j][r];
        *(uint2*)&Ts[e * 72 + wave * 16 + q * 4] = *(uint2*)&yb[j][0];
    }
    __syncthreads();

    {
        uint4* dstY = (uint4*)(Y + row0 * DD);
        const long b = row0 >> 10;
        const long mt = (row0 & 1023) >> 6;
        uint4* dstT = (uint4*)(YT + ((b * 16 + mt) * 128) * 64);
        #pragma unroll
        for (int i = 0; i < 4; ++i) {
            int idx = i * 256 + t;
            dstY[idx] = ((const uint4*)Ys)[idx];
            int e = idx >> 3, m = (idx & 7) * 8;
            dstT[idx] = *(const uint4*)&Ts[e * 72 + m];
        }
    }
}

// ---------- Kernel 2: fused proj_c + bilinear attention ----------------------
// Grid 512 = (b, nt); 4 waves x 16 n. Phase 1: Uc = relu(h_c Wu^T + b), Wu
// converted in-kernel. Phase 2: flash loop with double-buffered
// global_load_lds DMA staging (XOR-swizzled, unpadded), per-lane softmax
// (post-ReLU scores >= 0 -> no max), 1 barrier per mt. Epilogue: cross-wave
// LDS reduction (fixes the r7/r8 4-wave write race), then per-(b,nt) partial.
__global__ __launch_bounds__(256, 2) void attn_kernel(
    const float* __restrict__ hc,             // (B*512,128) fp32
    const float* __restrict__ Wu,             // (128,128) fp32
    const float* __restrict__ Ub,             // (128) fp32
    const unsigned short* __restrict__ Vp,    // (B,16,64,128) bf16 tiled
    const unsigned short* __restrict__ VpT,   // (B,16,128,64) bf16 tiled
    float* __restrict__ part)                 // (B*8,128) fp32
{
    // shorts: VsA[0,8192) VTsA[8192,16384) VsB[16384,24576) VTsB[24576,32768)
    //         Ps[32768,37376).  Phase1 alias: Ws[0,17408) Ucs[17408,26112).
    __shared__ __align__(16) unsigned short smem[37376];
    unsigned short* Ws  = smem;
    unsigned short* Ucs = smem + 17408;
    unsigned short* Ps  = smem + 32768;

    const int t = threadIdx.x;
    const int lane = t & 63;
    const int wave = t >> 6;
    const int n16 = lane & 15, q = lane >> 4;

    const int id = blockIdx.x;
    const int xcd = id & 7;
    const int slot = id >> 3;
    const int b = xcd * 8 + (slot >> 3);
    const int nt = slot & 7;

    const unsigned short* vpb = Vp + (long)b * MM * DD;    // 16 tiles of 8192
    const unsigned short* vtb = VpT + (long)b * MM * DD;

    // ---- Phase 1: Uc for this block's 64 n-rows (Wu fp32 -> bf16 in LDS) ----
    {
        const float4* Wg = (const float4*)Wu;
        #pragma unroll
        for (int i = 0; i < 16; ++i) {
            int idx = i * 256 + t;
            float4 v = Wg[idx];
            int off = idx * 4;
            uint2 u = { f2bf2(v.x, v.y), f2bf2(v.z, v.w) };
            *(uint2*)&Ws[(off >> 7) * 136 + (off & 127)] = u;
        }
    }
    __syncthreads();

    f32x4 acc[8];
    #pragma unroll
    for (int j = 0; j < 8; ++j) acc[j] = {0.f, 0.f, 0.f, 0.f};
    {
        const float* xrow = hc + ((long)b * NN + nt * 64 + wave * 16 + n16) * DD + q * 8;
        #pragma unroll
        for (int kk = 0; kk < 4; ++kk) {
            float4 x0 = *(const float4*)(xrow + kk * 32);
            float4 x1 = *(const float4*)(xrow + kk * 32 + 4);
            union { bf16x8 v; unsigned int u[4]; } a;
            a.u[0] = f2bf2(x0.x, x0.y); a.u[1] = f2bf2(x0.z, x0.w);
            a.u[2] = f2bf2(x1.x, x1.y); a.u[3] = f2bf2(x1.z, x1.w);
            #pragma unroll
            for (int j = 0; j < 8; ++j) {
                bf16x8 bb = *(const bf16x8*)&Ws[(j * 16 + n16) * 136 + q * 8 + kk * 32];
                acc[j] = __builtin_amdgcn_mfma_f32_16x16x32_bf16(a.v, bb, acc[j], 0, 0, 0);
            }
        }
    }
    float ucred[8];
    #pragma unroll
    for (int j = 0; j < 8; ++j) {
        const float bv = Ub[j * 16 + n16];
        float s = 0.f;
        #pragma unroll
        for (int r = 0; r < 4; ++r) {
            float v = acc[j][r] + bv;
            v = v > 0.f ? v : 0.f;
            s += v;
            Ucs[(wave * 16 + q * 4 + r) * 136 + j * 16 + n16] = f2bf(v);
        }
        ucred[j] = s;
    }
    __syncthreads();                                    // sync#2: Ucs ready, Ws dead

    bf16x8 Bg[4];
    #pragma unroll
    for (int kk = 0; kk < 4; ++kk)
        Bg[kk] = *(const bf16x8*)&Ucs[(wave * 16 + n16) * 136 + q * 8 + kk * 32];

    // DMA tile 0 into buffer A (Ws region — dead after sync#2).
    // Swizzle: chunk slot L -> row r, slot-col sc; data col c = sc ^ (r & 7).
    {
        #pragma unroll
        for (int i = 0; i < 4; ++i) {          // Vs: 1024 chunks (64 rows x 16)
            int L = wave * 256 + i * 64 + lane;
            int r = L >> 4, sc = L & 15, c = sc ^ (r & 7);
            async16(vpb + r * 128 + c * 8, smem + wave * 2048 + i * 512);
        }
        #pragma unroll
        for (int i = 0; i < 4; ++i) {          // VTs: 1024 chunks (128 rows x 8)
            int L = wave * 256 + i * 64 + lane;
            int r = L >> 3, sc = L & 7, c = sc ^ (r & 7);
            async16(vtb + r * 64 + c * 8, smem + 8192 + wave * 2048 + i * 512);
        }
    }
    __syncthreads();                                    // sync#3: Bg read done, DMA0 landed

    f32x4 O[8];
    #pragma unroll
    for (int j = 0; j < 8; ++j) O[j] = {0.f, 0.f, 0.f, 0.f};
    float lpart = 0.f;
    const float LOG2E = 1.44269504088896f;

    for (int mt = 0; mt < 16; ++mt) {
        const unsigned short* Vs  = smem + ((mt & 1) ? 16384 : 0);
        const unsigned short* VTs = Vs + 8192;
        unsigned short* nVs = smem + ((mt & 1) ? 0 : 16384);

        // issue DMA for tile mt+1 into the other buffer
        if (mt < 15) {
            const unsigned short* sv = vpb + (mt + 1) * 8192;
            const unsigned short* st = vtb + (mt + 1) * 8192;
            #pragma unroll
            for (int i = 0; i < 4; ++i) {
                int L = wave * 256 + i * 64 + lane;
                int r = L >> 4, sc = L & 15, c = sc ^ (r & 7);
                async16(sv + r * 128 + c * 8, nVs + wave * 2048 + i * 512);
            }
            #pragma unroll
            for (int i = 0; i < 4; ++i) {
                int L = wave * 256 + i * 64 + lane;
                int r = L >> 3, sc = L & 7, c = sc ^ (r & 7);
                async16(st + r * 64 + c * 8, nVs + 8192 + wave * 2048 + i * 512);
            }
        }

        // S^T = Vp_tile * Uc^T : reg r -> m = j*16 + q*4 + r, n = n16
        f32x4 S[4];
        #pragma unroll
        for (int j = 0; j < 4; ++j) S[j] = {0.f, 0.f, 0.f, 0.f};
        #pragma unroll
        for (int kk = 0; kk < 4; ++kk) {
            #pragma unroll
            for (int j = 0; j < 4; ++j) {
                int row = j * 16 + n16;
                int col = ((kk * 4 + q) ^ (n16 & 7)) * 8;
                bf16x8 a = *(const bf16x8*)&Vs[row * 128 + col];
                S[j] = __builtin_amdgcn_mfma_f32_16x16x32_bf16(a, Bg[kk], S[j], 0, 0, 0);
            }
        }

        // p = exp(s), per-lane only
        #pragma unroll
        for (int j = 0; j < 4; ++j) {
            float p0 = __builtin_exp2f(S[j][0] * LOG2E);
            float p1 = __builtin_exp2f(S[j][1] * LOG2E);
            float p2 = __builtin_exp2f(S[j][2] * LOG2E);
            float p3 = __builtin_exp2f(S[j][3] * LOG2E);
            lpart += (p0 + p1) + (p2 + p3);
            uint2 u = { f2bf2(p0, p1), f2bf2(p2, p3) };
            *(uint2*)&Ps[wave * 1152 + n16 * 72 + j * 16 + q * 4] = u;
        }

        // O += P * V : A = Ps rows (n, k=m), B = VTs rows (d, k=m)
        #pragma unroll
        for (int kk = 0; kk < 2; ++kk) {
            bf16x8 a = *(const bf16x8*)&Ps[wave * 1152 + n16 * 72 + kk * 32 + q * 8];
            #pragma unroll
            for (int j = 0; j < 8; ++j) {
                int row = j * 16 + n16;
                int col = ((kk * 4 + q) ^ (n16 & 7)) * 8;
                bf16x8 bb = *(const bf16x8*)&VTs[row * 64 + col];
                O[j] = __builtin_amdgcn_mfma_f32_16x16x32_bf16(a, bb, O[j], 0, 0, 0);
            }
        }
        __syncthreads();   // per-wave vmcnt drain => next-tile DMA landed; LDS safe
    }

    // l per n (lane n16 holds l for n = n16 after reduction)
    lpart += __shfl_xor(lpart, 16);
    lpart += __shfl_xor(lpart, 32);

    float inv[4];
    #pragma unroll
    for (int r = 0; r < 4; ++r)
        inv[r] = 1.0f / __shfl(lpart, q * 4 + r);

    // per-wave partial (this wave's 16 n-rows), then cross-wave LDS reduction
    float* red = (float*)Ps;    // 2048 B needed; Ps region is 9216 B, all reads done
    #pragma unroll
    for (int j = 0; j < 8; ++j) {
        float s = ucred[j]
                + O[j][0] * inv[0] + O[j][1] * inv[1]
                + O[j][2] * inv[2] + O[j][3] * inv[3];
        s += __shfl_xor(s, 16);
        s += __shfl_xor(s, 32);
        if (q == 0)
            red[wave * 128 + j * 16 + n16] = s;
    }
    __syncthreads();
    if (t < 128) {
        float tot = red[t] + red[128 + t] + red[256 + t] + red[384 + t];
        part[(long)(b * 8 + nt) * DD + t] = tot;
    }
}

// ---------- Kernel 3: out[b][d] = (Sigma_nt part) * q[d] / N -----------------
__global__ __launch_bounds__(256) void finalize_kernel(
    const float* __restrict__ part, const float* __restrict__ qv,
    float* __restrict__ out)
{
    int i = blockIdx.x * 256 + threadIdx.x;     // 8192
    int b = i >> 7, d = i & 127;
    const float* p = part + (long)b * 8 * DD + d;
    float s = 0.f;
    #pragma unroll
    for (int nt = 0; nt < 8; ++nt) s += p[nt * DD];
    out[i] = s * qv[d] * (1.0f / (float)NN);
}

extern "C" void kernel_launch(void* const* d_in, const int* in_sizes, int n_in,
                              void* d_out, int out_size, void* d_ws, size_t ws_size,
                              hipStream_t stream) {
    const float* h_c = (const float*)d_in[0];
    const float* h_p = (const float*)d_in[1];
    const float* U_w = (const float*)d_in[2];
    const float* U_b = (const float*)d_in[3];
    const float* V_w = (const float*)d_in[4];
    const float* V_b = (const float*)d_in[5];
    const float* qv  = (const float*)d_in[6];
    float* out = (float*)d_out;

    unsigned short* Vp  = (unsigned short*)d_ws;                 // (B,16,64,128) bf16
    unsigned short* VpT = Vp + (size_t)BB * MM * DD;             // (B,16,128,64) bf16
    float* part = (float*)(VpT + (size_t)BB * MM * DD);          // (B*8,128) fp32

    proj_v_kernel<<<BB * MM / 64, 256, 0, stream>>>(h_p, V_w, V_b, Vp, VpT);
    attn_kernel<<<512, 256, 0, stream>>>(h_c, U_w, U_b, Vp, VpT, part);
    finalize_kernel<<<32, 256, 0, stream>>>(part, qv, out);
}

// Round 10
// 129.806 us; speedup vs baseline: 1.5435x; 1.0079x over previous
//
#include <hip/hip_runtime.h>
#include <hip/hip_bf16.h>
#include <cstdint>

#define BB 64
#define NN 512
#define MM 1024
#define DD 128

typedef __bf16 bf16x8 __attribute__((ext_vector_type(8)));
typedef float f32x4 __attribute__((ext_vector_type(4)));

static __device__ __forceinline__ unsigned short f2bf(float f) {
    union { float f; unsigned int i; } v; v.f = f;
    unsigned int x = v.i;
    x += 0x7FFFu + ((x >> 16) & 1u);   // RNE
    return (unsigned short)(x >> 16);
}
// packed v_cvt_pk_bf16_f32: low = a, high = b
static __device__ __forceinline__ unsigned int f2bf2(float a, float b) {
    union { __hip_bfloat162 h; unsigned int u; } c;
    c.h = __float22bfloat162_rn(make_float2(a, b));
    return c.u;
}
// async global->LDS DMA, 16 B per lane, dest = wave-uniform base + lane*16
static __device__ __forceinline__ void async16(const void* g, void* l) {
    __builtin_amdgcn_global_load_lds(
        (const __attribute__((address_space(1))) void*)g,
        (__attribute__((address_space(3))) void*)l, 16, 0, 0);
}

// ---------- Kernel 1: Vp = relu(h_p @ Wv^T + b) ------------------------------
// Outputs: Vp row-major tiles [b][mt][64][128], VpT tiled [b][mt][128][64].
__global__ __launch_bounds__(256, 4) void proj_v_kernel(
    const float* __restrict__ X,
    const float* __restrict__ Wv,
    const float* __restrict__ bias,
    unsigned short* __restrict__ Y,
    unsigned short* __restrict__ YT)
{
    __shared__ __align__(16) unsigned short Ws[128 * 136];   // 34816 B, reused
    unsigned short* Ys = Ws;            // 64*128 shorts
    unsigned short* Ts = Ws + 8192;     // 128*72 shorts
    const int t = threadIdx.x;
    const int lane = t & 63;
    const int wave = t >> 6;
    const int n16 = lane & 15, q = lane >> 4;
    const long row0 = (long)blockIdx.x * 64;

    // X loads FIRST (latency overlaps W staging below)
    float4 xv[8];
    {
        const float* xrow = X + (row0 + wave * 16 + n16) * DD + q * 8;
        #pragma unroll
        for (int kk = 0; kk < 4; ++kk) {
            xv[2 * kk]     = *(const float4*)(xrow + kk * 32);
            xv[2 * kk + 1] = *(const float4*)(xrow + kk * 32 + 4);
        }
    }

    // stage Wv fp32 -> bf16 into padded LDS
    {
        const float4* Wg = (const float4*)Wv;
        #pragma unroll
        for (int i = 0; i < 16; ++i) {
            int idx = i * 256 + t;            // 4096 float4
            float4 v = Wg[idx];
            int off = idx * 4;                // shorts
            uint2 u = { f2bf2(v.x, v.y), f2bf2(v.z, v.w) };
            *(uint2*)&Ws[(off >> 7) * 136 + (off & 127)] = u;
        }
    }
    __syncthreads();

    f32x4 acc[8];
    #pragma unroll
    for (int j = 0; j < 8; ++j) acc[j] = {0.f, 0.f, 0.f, 0.f};

    #pragma unroll
    for (int kk = 0; kk < 4; ++kk) {
        float4 x0 = xv[2 * kk], x1 = xv[2 * kk + 1];
        union { bf16x8 v; unsigned int u[4]; } a;
        a.u[0] = f2bf2(x0.x, x0.y); a.u[1] = f2bf2(x0.z, x0.w);
        a.u[2] = f2bf2(x1.x, x1.y); a.u[3] = f2bf2(x1.z, x1.w);
        #pragma unroll
        for (int j = 0; j < 8; ++j) {
            bf16x8 b = *(const bf16x8*)&Ws[(j * 16 + n16) * 136 + q * 8 + kk * 32];
            acc[j] = __builtin_amdgcn_mfma_f32_16x16x32_bf16(a.v, b, acc[j], 0, 0, 0);
        }
    }

    unsigned short yb[8][4];
    #pragma unroll
    for (int j = 0; j < 8; ++j) {
        const float bv = bias[j * 16 + n16];
        float y[4];
        #pragma unroll
        for (int r = 0; r < 4; ++r) {
            float v = acc[j][r] + bv;
            y[r] = v > 0.f ? v : 0.f;
        }
        uint2 u = { f2bf2(y[0], y[1]), f2bf2(y[2], y[3]) };
        *(uint2*)&yb[j][0] = u;
    }
    __syncthreads();   // Ws reads done; reuse as Ys/Ts

    #pragma unroll
    for (int j = 0; j < 8; ++j) {
        const int e = j * 16 + n16;
        #pragma unroll
        for (int r = 0; r < 4; ++r)
            Ys[(wave * 16 + q * 4 + r) * 128 + e] = yb[j][r];
        *(uint2*)&Ts[e * 72 + wave * 16 + q * 4] = *(uint2*)&yb[j][0];
    }
    __syncthreads();

    {
        uint4* dstY = (uint4*)(Y + row0 * DD);
        const long b = row0 >> 10;
        const long mt = (row0 & 1023) >> 6;
        uint4* dstT = (uint4*)(YT + ((b * 16 + mt) * 128) * 64);
        #pragma unroll
        for (int i = 0; i < 4; ++i) {
            int idx = i * 256 + t;
            dstY[idx] = ((const uint4*)Ys)[idx];
            int e = idx >> 3, m = (idx & 7) * 8;
            dstT[idx] = *(const uint4*)&Ts[e * 72 + m];
        }
    }
}

// ---------- Kernel 2: fused proj_c + bilinear attention ----------------------
// Grid 512 = (b, nt); 4 waves. Phase 1: Uc = relu(h_c Wu^T + b), Wu converted
// in-kernel; Ucs stored PRE-SCALED by log2(e) (QK then feeds exp2 directly);
// fp32 unscaled row-sums kept in regs. Phase 2: m-split QK (each wave owns 16
// m-rows, B = all 64 Uc n-rows in 64 VGPRs -> 4 Vs reads/mt instead of 16),
// shared P through LDS, n-split PV. DMA double-buffer staging (XOR swizzle),
// DMA issued between the two barriers. Epilogue: cross-wave l + ctx reduction.
__global__ __launch_bounds__(256, 2) void attn_kernel(
    const float* __restrict__ hc,             // (B*512,128) fp32
    const float* __restrict__ Wu,             // (128,128) fp32
    const float* __restrict__ Ub,             // (128) fp32
    const unsigned short* __restrict__ Vp,    // (B,16,64,128) bf16 tiled
    const unsigned short* __restrict__ VpT,   // (B,16,128,64) bf16 tiled
    float* __restrict__ part)                 // (B*8,128) fp32
{
    // shorts: VsA[0,8192) VTsA[8192,16384) VsB[16384,24576) VTsB[24576,32768)
    //         Ps[32768,37376) (64 x 72).  Phase1 alias: Ws[0,17408) Ucs[17408,26112).
    __shared__ __align__(16) unsigned short smem[37376];
    unsigned short* Ws  = smem;
    unsigned short* Ucs = smem + 17408;
    unsigned short* Ps  = smem + 32768;

    const int t = threadIdx.x;
    const int lane = t & 63;
    const int wave = t >> 6;
    const int n16 = lane & 15, q = lane >> 4;

    const int id = blockIdx.x;
    const int xcd = id & 7;
    const int slot = id >> 3;
    const int b = xcd * 8 + (slot >> 3);
    const int nt = slot & 7;

    const unsigned short* vpb = Vp + (long)b * MM * DD;    // 16 tiles of 8192
    const unsigned short* vtb = VpT + (long)b * MM * DD;

    const float LOG2E = 1.44269504088896f;

    // ---- Phase 1: Uc for this block's 64 n-rows (Wu fp32 -> bf16 in LDS) ----
    {
        const float4* Wg = (const float4*)Wu;
        #pragma unroll
        for (int i = 0; i < 16; ++i) {
            int idx = i * 256 + t;
            float4 v = Wg[idx];
            int off = idx * 4;
            uint2 u = { f2bf2(v.x, v.y), f2bf2(v.z, v.w) };
            *(uint2*)&Ws[(off >> 7) * 136 + (off & 127)] = u;
        }
    }
    __syncthreads();

    f32x4 acc[8];
    #pragma unroll
    for (int j = 0; j < 8; ++j) acc[j] = {0.f, 0.f, 0.f, 0.f};
    {
        const float* xrow = hc + ((long)b * NN + nt * 64 + wave * 16 + n16) * DD + q * 8;
        #pragma unroll
        for (int kk = 0; kk < 4; ++kk) {
            float4 x0 = *(const float4*)(xrow + kk * 32);
            float4 x1 = *(const float4*)(xrow + kk * 32 + 4);
            union { bf16x8 v; unsigned int u[4]; } a;
            a.u[0] = f2bf2(x0.x, x0.y); a.u[1] = f2bf2(x0.z, x0.w);
            a.u[2] = f2bf2(x1.x, x1.y); a.u[3] = f2bf2(x1.z, x1.w);
            #pragma unroll
            for (int j = 0; j < 8; ++j) {
                bf16x8 bb = *(const bf16x8*)&Ws[(j * 16 + n16) * 136 + q * 8 + kk * 32];
                acc[j] = __builtin_amdgcn_mfma_f32_16x16x32_bf16(a.v, bb, acc[j], 0, 0, 0);
            }
        }
    }
    float ucred[8];
    #pragma unroll
    for (int j = 0; j < 8; ++j) {
        const float bv = Ub[j * 16 + n16];
        float s = 0.f;
        #pragma unroll
        for (int r = 0; r < 4; ++r) {
            float v = acc[j][r] + bv;
            v = v > 0.f ? v : 0.f;
            s += v;
            // store Uc * log2(e): QK output feeds exp2 directly
            Ucs[(wave * 16 + q * 4 + r) * 136 + j * 16 + n16] = f2bf(v * LOG2E);
        }
        ucred[j] = s;
    }
    __syncthreads();                                    // sync#2: Ucs ready, Ws dead

    // ALL 64 n-rows of Uc as B-frags in registers (16 frags = 64 VGPRs)
    bf16x8 Bg[4][4];
    #pragma unroll
    for (int j = 0; j < 4; ++j)
        #pragma unroll
        for (int kk = 0; kk < 4; ++kk)
            Bg[j][kk] = *(const bf16x8*)&Ucs[(j * 16 + n16) * 136 + q * 8 + kk * 32];

    // DMA tile 0 into buffer A (Ws region — dead after sync#2).
    // Swizzle: chunk slot L -> row r, slot-col sc; data col c = sc ^ (r & 7).
    {
        #pragma unroll
        for (int i = 0; i < 4; ++i) {          // Vs: 1024 chunks (64 rows x 16)
            int L = wave * 256 + i * 64 + lane;
            int r = L >> 4, sc = L & 15, c = sc ^ (r & 7);
            async16(vpb + r * 128 + c * 8, smem + wave * 2048 + i * 512);
        }
        #pragma unroll
        for (int i = 0; i < 4; ++i) {          // VTs: 1024 chunks (128 rows x 8)
            int L = wave * 256 + i * 64 + lane;
            int r = L >> 3, sc = L & 7, c = sc ^ (r & 7);
            async16(vtb + r * 64 + c * 8, smem + 8192 + wave * 2048 + i * 512);
        }
    }
    __syncthreads();                                    // sync#3: Bg read done, DMA0 landed

    f32x4 O[8];
    #pragma unroll
    for (int j = 0; j < 8; ++j) O[j] = {0.f, 0.f, 0.f, 0.f};
    float lpart[4] = {0.f, 0.f, 0.f, 0.f};

    for (int mt = 0; mt < 16; ++mt) {
        const unsigned short* Vs  = smem + ((mt & 1) ? 16384 : 0);
        const unsigned short* VTs = Vs + 8192;
        unsigned short* nVs = smem + ((mt & 1) ? 0 : 16384);

        // QK (m-split): this wave's 16 m-rows vs all 64 n.
        // S^T tile j: rows m = wave*16 + q*4 + r, cols n = j*16 + n16.
        f32x4 S[4];
        #pragma unroll
        for (int j = 0; j < 4; ++j) S[j] = {0.f, 0.f, 0.f, 0.f};
        #pragma unroll
        for (int kk = 0; kk < 4; ++kk) {
            int row = wave * 16 + n16;
            int col = ((kk * 4 + q) ^ (n16 & 7)) * 8;
            bf16x8 a = *(const bf16x8*)&Vs[row * 128 + col];
            #pragma unroll
            for (int j = 0; j < 4; ++j)
                S[j] = __builtin_amdgcn_mfma_f32_16x16x32_bf16(a, Bg[j][kk], S[j], 0, 0, 0);
        }

        // p = exp2(S) (Uc pre-scaled); write P[n][m] slices to shared Ps
        #pragma unroll
        for (int j = 0; j < 4; ++j) {
            float p0 = __builtin_exp2f(S[j][0]);
            float p1 = __builtin_exp2f(S[j][1]);
            float p2 = __builtin_exp2f(S[j][2]);
            float p3 = __builtin_exp2f(S[j][3]);
            lpart[j] += (p0 + p1) + (p2 + p3);
            uint2 u = { f2bf2(p0, p1), f2bf2(p2, p3) };
            // n = j*16 + n16, m = wave*16 + q*4 .. +3
            *(uint2*)&Ps[(j * 16 + n16) * 72 + wave * 16 + q * 4] = u;
        }
        __syncthreads();   // barrier 1: P complete (cross-wave exchange)

        // issue DMA for tile mt+1 (drained at barrier 2; PV phase covers latency)
        if (mt < 15) {
            const unsigned short* sv = vpb + (mt + 1) * 8192;
            const unsigned short* st = vtb + (mt + 1) * 8192;
            #pragma unroll
            for (int i = 0; i < 4; ++i) {
                int L = wave * 256 + i * 64 + lane;
                int r = L >> 4, sc = L & 15, c = sc ^ (r & 7);
                async16(sv + r * 128 + c * 8, nVs + wave * 2048 + i * 512);
            }
            #pragma unroll
            for (int i = 0; i < 4; ++i) {
                int L = wave * 256 + i * 64 + lane;
                int r = L >> 3, sc = L & 7, c = sc ^ (r & 7);
                async16(st + r * 64 + c * 8, nVs + 8192 + wave * 2048 + i * 512);
            }
        }

        // PV (n-split): O[n][d] for this wave's 16 n-rows.
        // A = Ps rows n = wave*16 + n16 (k = m), B = VTs rows d (k = m).
        #pragma unroll
        for (int kk = 0; kk < 2; ++kk) {
            bf16x8 a = *(const bf16x8*)&Ps[(wave * 16 + n16) * 72 + kk * 32 + q * 8];
            #pragma unroll
            for (int j = 0; j < 8; ++j) {
                int row = j * 16 + n16;
                int col = ((kk * 4 + q) ^ (n16 & 7)) * 8;
                bf16x8 bb = *(const bf16x8*)&VTs[row * 64 + col];
                O[j] = __builtin_amdgcn_mfma_f32_16x16x32_bf16(a, bb, O[j], 0, 0, 0);
            }
        }
        __syncthreads();   // barrier 2: Ps reads done + DMA drained; buffers safe
    }

    // ---- l reduction: lpart[j] covers n = j*16+n16 over this wave's m & q ----
    #pragma unroll
    for (int j = 0; j < 4; ++j) {
        lpart[j] += __shfl_xor(lpart[j], 16);
        lpart[j] += __shfl_xor(lpart[j], 32);
    }
    float* lred = (float*)Ps;               // 256 floats
    float* red  = (float*)Ps + 256;         // 512 floats
    if (q == 0) {
        #pragma unroll
        for (int j = 0; j < 4; ++j)
            lred[wave * 64 + j * 16 + n16] = lpart[j];
    }
    __syncthreads();

    float inv[4];
    #pragma unroll
    for (int r = 0; r < 4; ++r) {
        int n = wave * 16 + q * 4 + r;
        inv[r] = 1.0f / (lred[n] + lred[64 + n] + lred[128 + n] + lred[192 + n]);
    }

    // per-wave partial over its 16 n-rows, then cross-wave reduction
    #pragma unroll
    for (int j = 0; j < 8; ++j) {
        float s = ucred[j]
                + O[j][0] * inv[0] + O[j][1] * inv[1]
                + O[j][2] * inv[2] + O[j][3] * inv[3];
        s += __shfl_xor(s, 16);
        s += __shfl_xor(s, 32);
        if (q == 0)
            red[wave * 128 + j * 16 + n16] = s;
    }
    __syncthreads();
    if (t < 128) {
        float tot = red[t] + red[128 + t] + red[256 + t] + red[384 + t];
        part[(long)(b * 8 + nt) * DD + t] = tot;
    }
}

// ---------- Kernel 3: out[b][d] = (Sigma_nt part) * q[d] / N -----------------
__global__ __launch_bounds__(256) void finalize_kernel(
    const float* __restrict__ part, const float* __restrict__ qv,
    float* __restrict__ out)
{
    int i = blockIdx.x * 256 + threadIdx.x;     // 8192
    int b = i >> 7, d = i & 127;
    const float* p = part + (long)b * 8 * DD + d;
    float s = 0.f;
    #pragma unroll
    for (int nt = 0; nt < 8; ++nt) s += p[nt * DD];
    out[i] = s * qv[d] * (1.0f / (float)NN);
}

extern "C" void kernel_launch(void* const* d_in, const int* in_sizes, int n_in,
                              void* d_out, int out_size, void* d_ws, size_t ws_size,
                              hipStream_t stream) {
    const float* h_c = (const float*)d_in[0];
    const float* h_p = (const float*)d_in[1];
    const float* U_w = (const float*)d_in[2];
    const float* U_b = (const float*)d_in[3];
    const float* V_w = (const float*)d_in[4];
    const float* V_b = (const float*)d_in[5];
    const float* qv  = (const float*)d_in[6];
    float* out = (float*)d_out;

    unsigned short* Vp  = (unsigned short*)d_ws;                 // (B,16,64,128) bf16
    unsigned short* VpT = Vp + (size_t)BB * MM * DD;             // (B,16,128,64) bf16
    float* part = (float*)(VpT + (size_t)BB * MM * DD);          // (B*8,128) fp32

    proj_v_kernel<<<BB * MM / 64, 256, 0, stream>>>(h_p, V_w, V_b, Vp, VpT);
    attn_kernel<<<512, 256, 0, stream>>>(h_c, U_w, U_b, Vp, VpT, part);
    finalize_kernel<<<32, 256, 0, stream>>>(part, qv, out);
}